// Round 1
// 5088.393 us; speedup vs baseline: 2.2808x; 2.2808x over previous
//
#include <hip/hip_runtime.h>

// Problem dims
#define BATCH   256
#define T_STEPS 512
#define IN_DIM  256
#define HID     1024
#define KTOT    1280   // IN_DIM + HID
#define CKW     10     // K chunks of 32 per wave (2 x-chunks + 8 h-chunks)

// Dynamic LDS: 64 KB partials (q) + hs staging [64 rows][24 shorts] = 3072 B.
// Stride-24 rows (48 B) kill the 8-way bank conflict of the old [64][16]
// layout while keeping each half-row 16B-aligned for b128 re-reads.
#define DYN_LDS 68608

typedef __attribute__((ext_vector_type(4))) float f32x4;
typedef __attribute__((ext_vector_type(8))) short bf16x8;
typedef __attribute__((ext_vector_type(4))) short s16x4;

__device__ inline short f2bf(float f) {
    union { float f; unsigned u; } v; v.f = f;
    unsigned u = v.u;
    unsigned r = (u + 0x7fffu + ((u >> 16) & 1u)) >> 16;  // RNE
    return (short)r;
}

__device__ inline float sigmoidf_fast(float x) {
    return __builtin_amdgcn_rcpf(1.0f + __expf(-x));
}
__device__ inline float tanhf_fast(float x) {
    return 1.0f - 2.0f * __builtin_amdgcn_rcpf(1.0f + __expf(2.0f * x));
}

// full-line write-through store: 16 B, lands at the device coherence point
__device__ inline void store_wt16(void* p, f32x4 d) {
    asm volatile("global_store_dwordx4 %0, %1, off sc0 sc1" :: "v"(p), "v"(d) : "memory");
}

// Build w_cat bf16 [4096][1280] = [w_ih | w_hh] rows (N-major, K contiguous)
__global__ void prep_wcat(const float* __restrict__ wih, const float* __restrict__ whh,
                          short* __restrict__ wcat) {
    int i = blockIdx.x * 256 + threadIdx.x;
    if (i >= 4096 * KTOT) return;
    int g = i / KTOT;
    int k = i - g * KTOT;
    float v = (k < IN_DIM) ? wih[g * IN_DIM + k] : whh[(size_t)g * HID + (k - IN_DIM)];
    wcat[i] = f2bf(v);
}

// x [b][t][k] fp32 -> xt [t][b][k] bf16 (time-major: per-step slice contiguous)
__global__ void prep_xt(const float* __restrict__ x, short* __restrict__ xt) {
    int i = blockIdx.x * 256 + threadIdx.x;
    int o = i * 4;                    // output linear index, 4 elems/thread
    if (o >= BATCH * T_STEPS * IN_DIM) return;
    int k  = o & (IN_DIM - 1);
    int bt = o >> 8;
    int b  = bt & (BATCH - 1);
    int t  = bt >> 8;
    f32x4 v = *(const f32x4*)(x + ((size_t)(b * T_STEPS + t) << 8) + k);
    s16x4 s;
    s[0] = f2bf(v[0]); s[1] = f2bf(v[1]); s[2] = f2bf(v[2]); s[3] = f2bf(v[3]);
    *(s16x4*)(xt + o) = s;
}

// bias_comb = b_ih + b_hh; zero h buffers, barrier flags, output
__global__ void prep_misc(const float* __restrict__ bih, const float* __restrict__ bhh,
                          float* __restrict__ bias, short* __restrict__ h0,
                          short* __restrict__ h1, float* __restrict__ out,
                          int* __restrict__ flags) {
    int i = blockIdx.x * 256 + threadIdx.x;
    if (i < 4096) bias[i] = bih[i] + bhh[i];
    if (i < BATCH * HID) { h0[i] = 0; h1[i] = 0; }
    if (i < BATCH) out[i] = 0.0f;
    if (i < 256) flags[i] = 0;
}

// Persistent cooperative LSTM kernel, register-resident weights, custom
// per-m-group barrier, TILED h layout hT[jt][b][jr].
//
// Round-5 pipeline: K-chunks rebalanced so EVERY wave owns 2 x-chunks
// (h-independent) + 8 h-chunks. The x-MFMAs of step t+1 are issued in
// step t's tail, between the h write-through stores and the vmcnt(0)+flag,
// so store-ack / flag-propagation / consumer-poll latency hides under real
// work. Wave 0 alone stages+stores h and signals; wave 1 alone polls;
// buffer_inv sc1 executes on one wave only (caches are per-CU/per-XCD
// shared — 8x redundant invalidates removed).
//
// Grid: 256 blocks = 4 m-groups (64 rows) x 64 j-tiles (16 h-cols, 4 gates).
// Block: 512 threads = 8 waves = (m-half mh) x (K-quarter kw).
template<bool XBF>
__global__ __launch_bounds__(512, 2) void lstm_main(
    const float* __restrict__ x, const short* __restrict__ xt,
    const short* __restrict__ wcat, const float* __restrict__ bias,
    const float* __restrict__ fcw, const float* __restrict__ fcb,
    short* __restrict__ h0, short* __restrict__ h1,
    float* __restrict__ out, int* __restrict__ flags)
{
    extern __shared__ float q[];          // 64 KB partials + 3 KB h staging
    short* hs = (short*)(q + 16384);      // [64 rows][24 shorts] (16 used)

    const int tid = threadIdx.x;
    const int l   = tid & 63;
    const int u   = tid >> 6;        // wave 0..7
    const int mh  = u >> 2;          // m-half 0..1
    const int kw  = u & 3;           // K-quarter 0..3
    const int lq  = l >> 4;          // lane quad 0..3
    const int r16 = l & 15;
    const int grp = blockIdx.x >> 6;         // m-group 0..3
    const int jblk = blockIdx.x & 63;        // j-tile within group
    const int m0  = grp * 64;
    const int j0  = jblk * 16;
    const int jc  = j0 + r16;
    int* const gflags = flags + grp * 64;

    // ---- persistent B fragments: 10 chunks x 4 gates, register-resident ----
    // Chunk map per wave: i=0,1 -> x-chunk ci = kw*2+i (0..7);
    //                     i=2..9 -> h-chunk ci = 6+kw*8+i (8..39).
    // Exact cover of ci=0..39; K-reduce is order-invariant so any cover works.
    bf16x8 Bf[CKW][4];
    #pragma unroll
    for (int i = 0; i < CKW; ++i) {
        const int ci = (i < 2) ? (kw * 2 + i) : (6 + kw * 8 + i);
        const int k = ci * 32 + lq * 8;
        #pragma unroll
        for (int g = 0; g < 4; ++g)
            Bf[i][g] = *(const bf16x8*)(wcat + (size_t)(g * HID + jc) * KTOT + k);
    }

    // ---- update-phase cell ownership: 2 cells per thread ----
    const int mgrp  = u >> 1;            // 0..3
    const int rp    = (u & 1) * 2;       // r-pair base (0 or 2)
    const int mcell = mgrp * 16 + lq * 4 + rp;
    float bia[4];
    #pragma unroll
    for (int g = 0; g < 4; ++g) bia[g] = bias[g * HID + jc];
    float c0 = 0.f, c1 = 0.f;

    // ---- A-operand addressing ----
    const int mA0 = m0 + mh * 32 + r16;   // rows mA0 and mA0+16
    const float* xb0 = x + (size_t)mA0 * (T_STEPS * IN_DIM) + lq * 8;
    const float* xb1 = x + (size_t)(mA0 + 16) * (T_STEPS * IN_DIM) + lq * 8;

    f32x4 acc[2][4];

    // phase1: zero acc, accumulate the 2 x-chunks (h-independent)
    auto phase1 = [&](int tt) {
        #pragma unroll
        for (int ms = 0; ms < 2; ++ms)
            #pragma unroll
            for (int g = 0; g < 4; ++g)
                acc[ms][g] = (f32x4){0.f, 0.f, 0.f, 0.f};
        #pragma unroll
        for (int i = 0; i < 2; ++i) {
            const int ci = kw * 2 + i;
            bf16x8 a0, a1;
            if constexpr (XBF) {
                const short* p = xt + ((size_t)(tt * BATCH + mA0) << 8) + ci * 32 + lq * 8;
                a0 = *(const bf16x8*)p;
                a1 = *(const bf16x8*)(p + (16 << 8));
            } else {
                const float* p0 = xb0 + (size_t)tt * IN_DIM + ci * 32;
                const float* p1 = xb1 + (size_t)tt * IN_DIM + ci * 32;
                f32x4 u00 = ((const f32x4*)p0)[0], u01 = ((const f32x4*)p0)[1];
                f32x4 u10 = ((const f32x4*)p1)[0], u11 = ((const f32x4*)p1)[1];
                a0[0] = f2bf(u00[0]); a0[1] = f2bf(u00[1]); a0[2] = f2bf(u00[2]); a0[3] = f2bf(u00[3]);
                a0[4] = f2bf(u01[0]); a0[5] = f2bf(u01[1]); a0[6] = f2bf(u01[2]); a0[7] = f2bf(u01[3]);
                a1[0] = f2bf(u10[0]); a1[1] = f2bf(u10[1]); a1[2] = f2bf(u10[2]); a1[3] = f2bf(u10[3]);
                a1[4] = f2bf(u11[0]); a1[5] = f2bf(u11[1]); a1[6] = f2bf(u11[2]); a1[7] = f2bf(u11[3]);
            }
            #pragma unroll
            for (int g = 0; g < 4; ++g) {
                acc[0][g] = __builtin_amdgcn_mfma_f32_16x16x32_bf16(a0, Bf[i][g], acc[0][g], 0, 0, 0);
                acc[1][g] = __builtin_amdgcn_mfma_f32_16x16x32_bf16(a1, Bf[i][g], acc[1][g], 0, 0, 0);
            }
        }
    };

    phase1(0);

    for (int t = 0; t < T_STEPS; ++t) {
        const short* hcurT  = (t & 1) ? h1 : h0;
        short*       hnextT = (t & 1) ? h0 : h1;

        // ---- wait for h(t-1): wave 1 polls, one-wave cache invalidate ----
        if (t) {
            if (u == 1) {
                while (true) {
                    int v = __hip_atomic_load(&gflags[l], __ATOMIC_RELAXED,
                                              __HIP_MEMORY_SCOPE_AGENT);
                    if (__ballot(v < t) == 0ull) break;
                    __builtin_amdgcn_s_sleep(1);
                }
            }
            __syncthreads();
            if (u == 0) {
                asm volatile("buffer_inv sc1" ::: "memory");
                asm volatile("s_waitcnt vmcnt(0)" ::: "memory");
            }
            __syncthreads();   // L1/L2 dropped before any h load issues
        }

        // ---- h-part MFMAs (8 chunks from tiled layout hT[jt][b][jr]) ----
        #pragma unroll
        for (int i = 2; i < CKW; ++i) {
            const int ci = 6 + kw * 8 + i;
            const int k0 = ci * 32 - IN_DIM + lq * 8;
            const int jt = k0 >> 4;
            const int jr0 = k0 & 15;          // 0 or 8
            const short* hp = hcurT + ((size_t)(jt * BATCH + mA0) << 4) + jr0;
            bf16x8 a0 = *(const bf16x8*)hp;
            bf16x8 a1 = *(const bf16x8*)(hp + (16 << 4));
            #pragma unroll
            for (int g = 0; g < 4; ++g) {
                acc[0][g] = __builtin_amdgcn_mfma_f32_16x16x32_bf16(a0, Bf[i][g], acc[0][g], 0, 0, 0);
                acc[1][g] = __builtin_amdgcn_mfma_f32_16x16x32_bf16(a1, Bf[i][g], acc[1][g], 0, 0, 0);
            }
        }

        // ---- write K-partials to LDS (b128) ----
        #pragma unroll
        for (int ms = 0; ms < 2; ++ms)
            #pragma unroll
            for (int g = 0; g < 4; ++g)
                *(f32x4*)&q[(((kw * 4 + g) * 4 + mh * 2 + ms) * 64 + l) * 4] = acc[ms][g];
        __syncthreads();

        // ---- gather 4 K-partials via b128 reads (wave-uniform parity) ----
        float sA[4] = {0.f, 0.f, 0.f, 0.f};
        float sB[4] = {0.f, 0.f, 0.f, 0.f};
        if ((u & 1) == 0) {
            #pragma unroll
            for (int kk = 0; kk < 4; ++kk)
                #pragma unroll
                for (int g = 0; g < 4; ++g) {
                    f32x4 v = *(const f32x4*)&q[(((kk * 4 + g) * 4 + mgrp) * 64 + l) * 4];
                    sA[g] += v[0]; sB[g] += v[1];
                }
        } else {
            #pragma unroll
            for (int kk = 0; kk < 4; ++kk)
                #pragma unroll
                for (int g = 0; g < 4; ++g) {
                    f32x4 v = *(const f32x4*)&q[(((kk * 4 + g) * 4 + mgrp) * 64 + l) * 4];
                    sA[g] += v[2]; sB[g] += v[3];
                }
        }

        // ---- cell update for 2 cells, h -> LDS staging tile (stride 24) ----
        {
            float ig = sigmoidf_fast(sA[0] + bia[0]);
            float fg = sigmoidf_fast(sA[1] + bia[1]);
            float gg = tanhf_fast(sA[2] + bia[2]);
            float og = sigmoidf_fast(sA[3] + bia[3]);
            c0 = fg * c0 + ig * gg;
            hs[mcell * 24 + r16] = f2bf(og * tanhf_fast(c0));
        }
        {
            float ig = sigmoidf_fast(sB[0] + bia[0]);
            float fg = sigmoidf_fast(sB[1] + bia[1]);
            float gg = tanhf_fast(sB[2] + bia[2]);
            float og = sigmoidf_fast(sB[3] + bia[3]);
            c1 = fg * c1 + ig * gg;
            hs[(mcell + 1) * 24 + r16] = f2bf(og * tanhf_fast(c1));
        }

        // ---- tail: wave0 stores h slab; phase1(t+1) overlaps the ack ----
        if (t + 1 < T_STEPS) {
            __syncthreads();                 // hs tile complete
            if (u == 0) {
                #pragma unroll
                for (int hf = 0; hf < 2; ++hf) {
                    const int idx = hf * 64 + l;            // 0..127
                    f32x4 d = *(const f32x4*)((const char*)hs + (idx >> 1) * 48 + (idx & 1) * 16);
                    store_wt16(hnextT + ((size_t)(jblk * BATCH + m0) << 4) + idx * 8, d);
                }
            }
            phase1(t + 1);                   // x-MFMAs hide store-ack latency
            if (u == 0) {
                asm volatile("s_waitcnt vmcnt(0)" ::: "memory");
                if (l == 0)
                    __hip_atomic_store(&gflags[jblk], t + 1, __ATOMIC_RELAXED,
                                       __HIP_MEMORY_SCOPE_AGENT);
            }
        }
    }

    // ---- epilogue: out[b] = sum_j c[b,j]*fcw[j] + fcb ----
    const float fw = fcw[jc];
    float vA = c0 * fw, vB = c1 * fw;
    vA += __shfl_xor(vA, 1); vA += __shfl_xor(vA, 2);
    vA += __shfl_xor(vA, 4); vA += __shfl_xor(vA, 8);
    vB += __shfl_xor(vB, 1); vB += __shfl_xor(vB, 2);
    vB += __shfl_xor(vB, 4); vB += __shfl_xor(vB, 8);
    if (r16 == 0) {
        float add = (j0 == 0) ? fcb[0] : 0.f;
        atomicAdd(&out[m0 + mcell],     vA + add);
        atomicAdd(&out[m0 + mcell + 1], vB + add);
    }
}

extern "C" void kernel_launch(void* const* d_in, const int* in_sizes, int n_in,
                              void* d_out, int out_size, void* d_ws, size_t ws_size,
                              hipStream_t stream)
{
    (void)in_sizes; (void)n_in; (void)out_size;
    const float* x   = (const float*)d_in[0];
    const float* wih = (const float*)d_in[1];
    const float* whh = (const float*)d_in[2];
    const float* bih = (const float*)d_in[3];
    const float* bhh = (const float*)d_in[4];
    const float* fcw = (const float*)d_in[5];
    const float* fcb = (const float*)d_in[6];
    float* out = (float*)d_out;

    char* ws = (char*)d_ws;
    short* wcat  = (short*)ws;                                  // 10,485,760 B
    float* bias  = (float*)(ws + 10485760);                     // 16,384 B
    short* h0    = (short*)(ws + 10485760 + 16384);             // 524,288 B (tiled)
    short* h1    = h0 + BATCH * HID;                            // 524,288 B (tiled)
    int*   flags = (int*)(ws + 10485760 + 16384 + 2 * 524288);  // 1,024 B
    short* xt    = (short*)(ws + 11551744);                     // 67,108,864 B
    const size_t WS_NEEDED = 11551744ull + 67108864ull;         // 78,660,608 B
    const bool use_xbf = (ws_size >= WS_NEEDED);

    prep_wcat<<<(4096 * KTOT + 255) / 256, 256, 0, stream>>>(wih, whh, wcat);
    prep_misc<<<(BATCH * HID + 255) / 256, 256, 0, stream>>>(bih, bhh, bias, h0, h1, out, flags);
    if (use_xbf)
        prep_xt<<<(BATCH * T_STEPS * IN_DIM / 4 + 255) / 256, 256, 0, stream>>>(x, xt);

    void* fn = use_xbf ? (void*)lstm_main<true> : (void*)lstm_main<false>;
    hipFuncSetAttribute(fn, hipFuncAttributeMaxDynamicSharedMemorySize, DYN_LDS);

    void* args[] = { (void*)&x, (void*)&xt, (void*)&wcat, (void*)&bias,
                     (void*)&fcw, (void*)&fcb, (void*)&h0, (void*)&h1,
                     (void*)&out, (void*)&flags };
    hipLaunchCooperativeKernel(fn, dim3(256), dim3(512), args, DYN_LDS, stream);
}

// Round 3
// 3530.556 us; speedup vs baseline: 3.2872x; 1.4412x over previous
//
#include <hip/hip_runtime.h>

// Problem dims
#define BATCH   256
#define T_STEPS 512
#define IN_DIM  256
#define HID     1024
#define KTOT    1280   // IN_DIM + HID
#define CKW     10     // K chunks of 32 per wave (2 x-chunks + 8 h-chunks)

// Dynamic LDS: 64 KB partials (q) + hs staging [2][32][16] shorts = 2 KB.
#define DYN_LDS 67584

typedef __attribute__((ext_vector_type(4))) float f32x4;
typedef __attribute__((ext_vector_type(8))) short bf16x8;
typedef __attribute__((ext_vector_type(4))) short s16x4;

__device__ inline short f2bf(float f) {
    union { float f; unsigned u; } v; v.f = f;
    unsigned u = v.u;
    unsigned r = (u + 0x7fffu + ((u >> 16) & 1u)) >> 16;  // RNE
    return (short)r;
}

__device__ inline float sigmoidf_fast(float x) {
    return __builtin_amdgcn_rcpf(1.0f + __expf(-x));
}
__device__ inline float tanhf_fast(float x) {
    return 1.0f - 2.0f * __builtin_amdgcn_rcpf(1.0f + __expf(2.0f * x));
}

// write-through to device coherence point (LLC) — slow/fallback path
__device__ inline void store_wt16(void* p, f32x4 d) {
    asm volatile("global_store_dwordx4 %0, %1, off sc0 sc1" :: "v"(p), "v"(d) : "memory");
}

// Build w_cat bf16 [4096][1280] = [w_ih | w_hh] rows (N-major, K contiguous)
__global__ void prep_wcat(const float* __restrict__ wih, const float* __restrict__ whh,
                          short* __restrict__ wcat) {
    int i = blockIdx.x * 256 + threadIdx.x;
    if (i >= 4096 * KTOT) return;
    int g = i / KTOT;
    int k = i - g * KTOT;
    float v = (k < IN_DIM) ? wih[g * IN_DIM + k] : whh[(size_t)g * HID + (k - IN_DIM)];
    wcat[i] = f2bf(v);
}

// x [b][t][k] fp32 -> xt [t][b][k] bf16 (time-major: per-step slice contiguous)
__global__ void prep_xt(const float* __restrict__ x, short* __restrict__ xt) {
    int i = blockIdx.x * 256 + threadIdx.x;
    int o = i * 4;                    // output linear index, 4 elems/thread
    if (o >= BATCH * T_STEPS * IN_DIM) return;
    int k  = o & (IN_DIM - 1);
    int bt = o >> 8;
    int b  = bt & (BATCH - 1);
    int t  = bt >> 8;
    f32x4 v = *(const f32x4*)(x + ((size_t)(b * T_STEPS + t) << 8) + k);
    s16x4 s;
    s[0] = f2bf(v[0]); s[1] = f2bf(v[1]); s[2] = f2bf(v[2]); s[3] = f2bf(v[3]);
    *(s16x4*)(xt + o) = s;
}

// sync[] layout (ints): [0..255] flags, [256..319] ctrl, [320..575] pready,
// [576..8767] probe tokens (stride 32 ints = 128 B, line-exclusive per block)
#define SYNC_INTS 8768
#define C_BAR     256   // grid-barrier counter
#define C_IMPURE  257   // any-group-impure flag
#define PREADY    320
#define PROBE     576

// bias_comb = b_ih + b_hh; zero h buffers, sync block, output
__global__ void prep_misc(const float* __restrict__ bih, const float* __restrict__ bhh,
                          float* __restrict__ bias, short* __restrict__ h0,
                          short* __restrict__ h1, float* __restrict__ out,
                          int* __restrict__ sync) {
    int i = blockIdx.x * 256 + threadIdx.x;
    if (i < 4096) bias[i] = bih[i] + bhh[i];
    if (i < BATCH * HID) { h0[i] = 0; h1[i] = 0; }
    if (i < BATCH) out[i] = 0.0f;
    if (i < SYNC_INTS) sync[i] = 0;
}

// Persistent cooperative LSTM. Round-7: XCD-local h exchange, de-risked.
//
// 8 groups x 32 batch rows x 32 blocks; group = blockIdx&7 (HW round-robin
// XCD mapping). Bulk h data: plain stores -> dirty in the XCD's L2; plain
// loads after an L1-only buffer_inv. Flag handshake stays on the PROVEN
// round-1 primitive (__hip_atomic RELAXED/AGENT at the LLC); explicit
// s_waitcnt vmcnt(0) orders h-stores before the flag store.
//
// Whether a group really shares one L2 is verified EMPIRICALLY at startup:
// each block plain-stores a token, vmcnt(0), AGENT-ready; consumers
// AGENT-poll ready (always terminates), L1-inv, plain-load the 31 partner
// tokens. Any miss => ALL groups fall back to the round-1 LLC protocol
// (mixed mode unsafe: sc1 inv would discard fast-path dirty L2 lines).
// No spin ever waits on a plain (non-coherent) location => no deadlock.
template<bool XBF>
__global__ __launch_bounds__(512, 2) void lstm_main(
    const float* __restrict__ x, const short* __restrict__ xt,
    const short* __restrict__ wcat, const float* __restrict__ bias,
    const float* __restrict__ fcw, const float* __restrict__ fcb,
    short* __restrict__ h0, short* __restrict__ h1,
    float* __restrict__ out, int* __restrict__ sync)
{
    extern __shared__ float q[];          // 64 KB partials + 2 KB h staging
    short* hs = (short*)(q + 16384);      // [2 col-halves][32 rows][16]

    const int tid = threadIdx.x;
    const int l   = tid & 63;
    const int u   = tid >> 6;        // wave 0..7
    const int nh  = u >> 2;          // N-half (which 16 of the 32 j-cols)
    const int kw  = u & 3;           // K-quarter
    const int lq  = l >> 4;          // lane quad 0..3
    const int r16 = l & 15;

    const int grp  = blockIdx.x & 7;     // XCD (HW round-robin assumption)
    const int jblk = blockIdx.x >> 3;    // j-tile within group, 0..31
    const int vb   = grp * 32 + jblk;
    const int m0   = grp * 32;           // 32 batch rows per group
    const int j0   = jblk * 32;          // 32 h-cols per block
    const int jc   = j0 + nh * 16 + r16;
    int* const gflags = sync + grp * 32;

    // ================= empirical same-L2 probe =================
    int* sb = (int*)q;
    if (tid == 0) {
        sync[PROBE + vb * 32] = 0x5EED0000 + vb;            // plain store -> L2
        asm volatile("s_waitcnt vmcnt(0)" ::: "memory");    // token at L2
        __hip_atomic_store(&sync[PREADY + vb], 1, __ATOMIC_RELAXED,
                           __HIP_MEMORY_SCOPE_AGENT);       // LLC-coherent
    }
    if (u == 1) {        // wait for all group members' ready flags (LLC)
        while (true) {
            int v = __hip_atomic_load(&sync[PREADY + grp * 32 + (l & 31)],
                                      __ATOMIC_RELAXED, __HIP_MEMORY_SCOPE_AGENT);
            if (__ballot(v == 0) == 0ull) break;
            __builtin_amdgcn_s_sleep(1);
        }
    }
    __syncthreads();
    if (u == 0) {
        asm volatile("buffer_inv" ::: "memory");            // L1 only
        asm volatile("s_waitcnt vmcnt(0)" ::: "memory");
    }
    __syncthreads();
    if (u == 0) {        // plain-load partner tokens: visible iff same L2
        int ok = 1;
        if (l < 32) {
            int exp = 0x5EED0000 + grp * 32 + l;
            ok = (sync[PROBE + (grp * 32 + l) * 32] == exp);
        }
        unsigned long long m = __ballot(ok);
        if (l == 0) sb[0] = (m == ~0ull) ? 1 : 0;
    }
    __syncthreads();
    const int grp_ok = sb[0];
    if (tid == 0) {
        if (!grp_ok)
            __hip_atomic_store(&sync[C_IMPURE], 1, __ATOMIC_RELAXED,
                               __HIP_MEMORY_SCOPE_AGENT);
        __hip_atomic_fetch_add(&sync[C_BAR], 1, __ATOMIC_ACQ_REL,
                               __HIP_MEMORY_SCOPE_AGENT);
        while (__hip_atomic_load(&sync[C_BAR], __ATOMIC_ACQUIRE,
                                 __HIP_MEMORY_SCOPE_AGENT) < 256)
            __builtin_amdgcn_s_sleep(8);
        sb[1] = !__hip_atomic_load(&sync[C_IMPURE], __ATOMIC_RELAXED,
                                   __HIP_MEMORY_SCOPE_AGENT);
    }
    __syncthreads();
    const int fast = sb[1];
    __syncthreads();          // sb dead; q free for partials

    // ---- persistent B fragments: 10 chunks x 4 gates, register-resident ----
    // i=0,1 -> x-chunk ci = kw*2+i (0..7); i=2..9 -> h-chunk ci = 6+kw*8+i.
    bf16x8 Bf[CKW][4];
    #pragma unroll
    for (int i = 0; i < CKW; ++i) {
        const int ci = (i < 2) ? (kw * 2 + i) : (6 + kw * 8 + i);
        const int k = ci * 32 + lq * 8;
        #pragma unroll
        for (int g = 0; g < 4; ++g)
            Bf[i][g] = *(const bf16x8*)(wcat + (size_t)(g * HID + jc) * KTOT + k);
    }

    // ---- update-phase cell ownership: 2 cells per thread ----
    const int s_u  = u >> 1;             // subtile = nh*2 + ms
    const int ms_u = s_u & 1;
    const int rp   = (u & 1) * 2;
    const int row0 = ms_u * 16 + lq * 4 + rp;     // rows row0, row0+1 (of 32)
    float bia[4];
    #pragma unroll
    for (int g = 0; g < 4; ++g) bia[g] = bias[g * HID + jc];
    float c0 = 0.f, c1 = 0.f;

    // ---- A-operand addressing: rows mA0, mA0+16 ----
    const int mA0 = m0 + r16;
    const float* xb0 = x + (size_t)mA0 * (T_STEPS * IN_DIM) + lq * 8;
    const float* xb1 = x + (size_t)(mA0 + 16) * (T_STEPS * IN_DIM) + lq * 8;

    f32x4 acc[2][4];

    // phase1: zero acc, accumulate the 2 x-chunks (h-independent)
    auto phase1 = [&](int tt) {
        #pragma unroll
        for (int ms = 0; ms < 2; ++ms)
            #pragma unroll
            for (int g = 0; g < 4; ++g)
                acc[ms][g] = (f32x4){0.f, 0.f, 0.f, 0.f};
        #pragma unroll
        for (int i = 0; i < 2; ++i) {
            const int ci = kw * 2 + i;
            bf16x8 a0, a1;
            if constexpr (XBF) {
                const short* p = xt + ((size_t)(tt * BATCH + mA0) << 8) + ci * 32 + lq * 8;
                a0 = *(const bf16x8*)p;
                a1 = *(const bf16x8*)(p + (16 << 8));
            } else {
                const float* p0 = xb0 + (size_t)tt * IN_DIM + ci * 32;
                const float* p1 = xb1 + (size_t)tt * IN_DIM + ci * 32;
                f32x4 u00 = ((const f32x4*)p0)[0], u01 = ((const f32x4*)p0)[1];
                f32x4 u10 = ((const f32x4*)p1)[0], u11 = ((const f32x4*)p1)[1];
                a0[0] = f2bf(u00[0]); a0[1] = f2bf(u00[1]); a0[2] = f2bf(u00[2]); a0[3] = f2bf(u00[3]);
                a0[4] = f2bf(u01[0]); a0[5] = f2bf(u01[1]); a0[6] = f2bf(u01[2]); a0[7] = f2bf(u01[3]);
                a1[0] = f2bf(u10[0]); a1[1] = f2bf(u10[1]); a1[2] = f2bf(u10[2]); a1[3] = f2bf(u10[3]);
                a1[4] = f2bf(u11[0]); a1[5] = f2bf(u11[1]); a1[6] = f2bf(u11[2]); a1[7] = f2bf(u11[3]);
            }
            #pragma unroll
            for (int g = 0; g < 4; ++g) {
                acc[0][g] = __builtin_amdgcn_mfma_f32_16x16x32_bf16(a0, Bf[i][g], acc[0][g], 0, 0, 0);
                acc[1][g] = __builtin_amdgcn_mfma_f32_16x16x32_bf16(a1, Bf[i][g], acc[1][g], 0, 0, 0);
            }
        }
    };

    phase1(0);

    for (int t = 0; t < T_STEPS; ++t) {
        const short* hcurT  = (t & 1) ? h1 : h0;
        short*       hnextT = (t & 1) ? h0 : h1;

        // ---- wait for h(t-1): wave 1 polls LLC flags; inv before h loads ----
        if (t) {
            if (u == 1) {
                while (true) {
                    int v = __hip_atomic_load(&gflags[l & 31], __ATOMIC_RELAXED,
                                              __HIP_MEMORY_SCOPE_AGENT);
                    if (__ballot(v < t) == 0ull) break;
                    __builtin_amdgcn_s_sleep(1);
                }
            }
            __syncthreads();
            if (u == 0) {
                if (fast) asm volatile("buffer_inv" ::: "memory");      // L1 only
                else      asm volatile("buffer_inv sc1" ::: "memory");  // L1+L2
                asm volatile("s_waitcnt vmcnt(0)" ::: "memory");
            }
            __syncthreads();
        }

        // ---- h-part MFMAs (8 chunks from tiled layout hT[jt][b][jr]) ----
        #pragma unroll
        for (int i = 2; i < CKW; ++i) {
            const int ci = 6 + kw * 8 + i;
            const int k0 = ci * 32 - IN_DIM + lq * 8;
            const int jt = k0 >> 4;
            const int jr0 = k0 & 15;          // 0 or 8
            const short* hp = hcurT + ((size_t)(jt * BATCH + mA0) << 4) + jr0;
            bf16x8 a0 = *(const bf16x8*)hp;
            bf16x8 a1 = *(const bf16x8*)(hp + (16 << 4));
            #pragma unroll
            for (int g = 0; g < 4; ++g) {
                acc[0][g] = __builtin_amdgcn_mfma_f32_16x16x32_bf16(a0, Bf[i][g], acc[0][g], 0, 0, 0);
                acc[1][g] = __builtin_amdgcn_mfma_f32_16x16x32_bf16(a1, Bf[i][g], acc[1][g], 0, 0, 0);
            }
        }

        // ---- write K-partials to LDS (b128): subtile id = nh*2+ms ----
        #pragma unroll
        for (int ms = 0; ms < 2; ++ms)
            #pragma unroll
            for (int g = 0; g < 4; ++g)
                *(f32x4*)&q[(((kw * 4 + g) * 4 + nh * 2 + ms) * 64 + l) * 4] = acc[ms][g];
        __syncthreads();

        // ---- gather 4 K-partials via b128 reads (wave-uniform parity) ----
        float sA[4] = {0.f, 0.f, 0.f, 0.f};
        float sB[4] = {0.f, 0.f, 0.f, 0.f};
        if ((u & 1) == 0) {
            #pragma unroll
            for (int kk = 0; kk < 4; ++kk)
                #pragma unroll
                for (int g = 0; g < 4; ++g) {
                    f32x4 v = *(const f32x4*)&q[(((kk * 4 + g) * 4 + s_u) * 64 + l) * 4];
                    sA[g] += v[0]; sB[g] += v[1];
                }
        } else {
            #pragma unroll
            for (int kk = 0; kk < 4; ++kk)
                #pragma unroll
                for (int g = 0; g < 4; ++g) {
                    f32x4 v = *(const f32x4*)&q[(((kk * 4 + g) * 4 + s_u) * 64 + l) * 4];
                    sA[g] += v[2]; sB[g] += v[3];
                }
        }

        // ---- cell update for 2 cells, h -> LDS staging [nh][row][r16] ----
        {
            float ig = sigmoidf_fast(sA[0] + bia[0]);
            float fg = sigmoidf_fast(sA[1] + bia[1]);
            float gg = tanhf_fast(sA[2] + bia[2]);
            float og = sigmoidf_fast(sA[3] + bia[3]);
            c0 = fg * c0 + ig * gg;
            hs[nh * 512 + row0 * 16 + r16] = f2bf(og * tanhf_fast(c0));
        }
        {
            float ig = sigmoidf_fast(sB[0] + bia[0]);
            float fg = sigmoidf_fast(sB[1] + bia[1]);
            float gg = tanhf_fast(sB[2] + bia[2]);
            float og = sigmoidf_fast(sB[3] + bia[3]);
            c1 = fg * c1 + ig * gg;
            hs[nh * 512 + (row0 + 1) * 16 + r16] = f2bf(og * tanhf_fast(c1));
        }

        // ---- tail: wave0 stores h slab; phase1(t+1) overlaps the ack ----
        if (t + 1 < T_STEPS) {
            __syncthreads();                 // hs tile complete
            if (u == 0) {
                #pragma unroll
                for (int hf = 0; hf < 2; ++hf) {
                    const int idx = hf * 64 + l;            // 0..127
                    const int ch  = idx >> 6;               // col-half -> jt
                    const int q16 = idx & 63;               // (row, jr-half)
                    f32x4 d = *(const f32x4*)((const char*)hs + idx * 16);
                    short* dst = hnextT
                        + (((size_t)((jblk * 2 + ch) * BATCH + m0 + (q16 >> 1))) << 4)
                        + (q16 & 1) * 8;
                    if (fast) *(f32x4*)dst = d;             // plain -> own L2
                    else      store_wt16(dst, d);           // LLC write-through
                }
            }
            phase1(t + 1);                   // x-MFMAs hide store-ack latency
            if (u == 0) {
                asm volatile("s_waitcnt vmcnt(0)" ::: "memory");  // h at L2/LLC
                if (l == 0)
                    __hip_atomic_store(&gflags[jblk], t + 1, __ATOMIC_RELAXED,
                                       __HIP_MEMORY_SCOPE_AGENT); // LLC flag
            }
        }
    }

    // ---- epilogue: out[b] = sum_j c[b,j]*fcw[j] + fcb ----
    const float fw = fcw[jc];
    float vA = c0 * fw, vB = c1 * fw;
    vA += __shfl_xor(vA, 1); vA += __shfl_xor(vA, 2);
    vA += __shfl_xor(vA, 4); vA += __shfl_xor(vA, 8);
    vB += __shfl_xor(vB, 1); vB += __shfl_xor(vB, 2);
    vB += __shfl_xor(vB, 4); vB += __shfl_xor(vB, 8);
    if (r16 == 0) {
        float add = (j0 == 0 && nh == 0) ? fcb[0] : 0.f;   // once per row
        atomicAdd(&out[m0 + row0],     vA + add);
        atomicAdd(&out[m0 + row0 + 1], vB + add);
    }
}

extern "C" void kernel_launch(void* const* d_in, const int* in_sizes, int n_in,
                              void* d_out, int out_size, void* d_ws, size_t ws_size,
                              hipStream_t stream)
{
    (void)in_sizes; (void)n_in; (void)out_size;
    const float* x   = (const float*)d_in[0];
    const float* wih = (const float*)d_in[1];
    const float* whh = (const float*)d_in[2];
    const float* bih = (const float*)d_in[3];
    const float* bhh = (const float*)d_in[4];
    const float* fcw = (const float*)d_in[5];
    const float* fcb = (const float*)d_in[6];
    float* out = (float*)d_out;

    char* ws = (char*)d_ws;
    short* wcat  = (short*)ws;                                  // 10,485,760 B
    float* bias  = (float*)(ws + 10485760);                     // 16,384 B
    short* h0    = (short*)(ws + 10485760 + 16384);             // 524,288 B (tiled)
    short* h1    = h0 + BATCH * HID;                            // 524,288 B (tiled)
    int*   sync  = (int*)(ws + 11550720);                       // 35,072 B
    short* xt    = (short*)(ws + 11585792);                     // 67,108,864 B
    const size_t WS_NEEDED = 11585792ull + 67108864ull;         // 78,694,656 B
    const bool use_xbf = (ws_size >= WS_NEEDED);

    prep_wcat<<<(4096 * KTOT + 255) / 256, 256, 0, stream>>>(wih, whh, wcat);
    prep_misc<<<(BATCH * HID + 255) / 256, 256, 0, stream>>>(bih, bhh, bias, h0, h1, out, sync);
    if (use_xbf)
        prep_xt<<<(BATCH * T_STEPS * IN_DIM / 4 + 255) / 256, 256, 0, stream>>>(x, xt);

    void* fn = use_xbf ? (void*)lstm_main<true> : (void*)lstm_main<false>;
    hipFuncSetAttribute(fn, hipFuncAttributeMaxDynamicSharedMemorySize, DYN_LDS);

    void* args[] = { (void*)&x, (void*)&xt, (void*)&wcat, (void*)&bias,
                     (void*)&fcw, (void*)&fcb, (void*)&h0, (void*)&h1,
                     (void*)&out, (void*)&sync };
    hipLaunchCooperativeKernel(fn, dim3(256), dim3(512), args, DYN_LDS, stream);
}